// Round 2
// baseline (748.177 us; speedup 1.0000x reference)
//
#include <hip/hip_runtime.h>
#include <hip/hip_bf16.h>

// GCN 2-layer forward on MI355X — CSR-gather version (no f32 scatter atomics).
// Inputs: x[N,512] f32, edge_index[2,E] int32, edge_weight[E] f32,
//         W1[512,16], b1[16], W2[16,10], b2[10]
// Outputs (concat): log_softmax(logits)[N,10], x1[N,16]

#define NF1 16   // hidden
#define NF2 10   // classes
#define FIN 512

typedef unsigned long long ull;

// ---------- degree + incoming-edge count ----------
__global__ __launch_bounds__(256) void init_deg_cnt_kernel(float* __restrict__ deg,
                                                           int* __restrict__ cnt, int N) {
    int i = blockIdx.x * 256 + threadIdx.x;
    if (i < N) { deg[i] = 1.0f; cnt[i] = 1; }   // self-loop: weight 1, one CSR slot
}

__global__ __launch_bounds__(256) void edge_count_kernel(const int* __restrict__ col,
                                                         const float* __restrict__ ew,
                                                         float* __restrict__ deg,
                                                         int* __restrict__ cnt, int E) {
    int e = blockIdx.x * 256 + threadIdx.x;
    if (e < E) {
        int c = col[e];
        unsafeAtomicAdd(&deg[c], ew[e]);
        atomicAdd(&cnt[c], 1);
    }
}

__global__ __launch_bounds__(256) void dinv_kernel(float* __restrict__ deg, int N) {
    int i = blockIdx.x * 256 + threadIdx.x;
    if (i < N) {
        float d = deg[i];
        deg[i] = (d > 0.0f) ? rsqrtf(d) : 0.0f;
    }
}

// ---------- prefix sum: cnt -> rowptr (exclusive), head copy ----------
__global__ __launch_bounds__(256) void block_sum_kernel(const int* __restrict__ cnt,
                                                        int* __restrict__ part, int N) {
    __shared__ int s[256];
    int i = blockIdx.x * 256 + threadIdx.x;
    s[threadIdx.x] = (i < N) ? cnt[i] : 0;
    __syncthreads();
    for (int off = 128; off > 0; off >>= 1) {
        if (threadIdx.x < off) s[threadIdx.x] += s[threadIdx.x + off];
        __syncthreads();
    }
    if (threadIdx.x == 0) part[blockIdx.x] = s[0];
}

__global__ __launch_bounds__(1024) void part_scan_kernel(int* __restrict__ part, int nb) {
    __shared__ int s[1024];
    int t = threadIdx.x;
    int v = (t < nb) ? part[t] : 0;
    s[t] = v;
    __syncthreads();
    for (int off = 1; off < 1024; off <<= 1) {
        int u = (t >= off) ? s[t - off] : 0;
        __syncthreads();
        s[t] += u;
        __syncthreads();
    }
    if (t < nb) part[t] = s[t] - v;   // exclusive
}

__global__ __launch_bounds__(256) void scan_apply_kernel(const int* __restrict__ cnt,
                                                         const int* __restrict__ part,
                                                         int* __restrict__ rowptr,
                                                         int* __restrict__ head,
                                                         int N, int total) {
    __shared__ int s[256];
    int t = threadIdx.x;
    int i = blockIdx.x * 256 + t;
    int v = (i < N) ? cnt[i] : 0;
    s[t] = v;
    __syncthreads();
    for (int off = 1; off < 256; off <<= 1) {
        int u = (t >= off) ? s[t - off] : 0;
        __syncthreads();
        s[t] += u;
        __syncthreads();
    }
    int excl = s[t] - v + part[blockIdx.x];
    if (i < N) {
        rowptr[i] = excl;
        head[i] = excl;
        if (i == N - 1) rowptr[N] = total;
    }
}

// ---------- CSR fill: csr[pos] = pack(norm, src_row) ----------
__global__ __launch_bounds__(256) void fill_edges_kernel(const int* __restrict__ row,
                                                         const int* __restrict__ col,
                                                         const float* __restrict__ ew,
                                                         const float* __restrict__ dinv,
                                                         int* __restrict__ head,
                                                         ull* __restrict__ csr, int E) {
    int e = blockIdx.x * 256 + threadIdx.x;
    if (e >= E) return;
    int r = row[e], c = col[e];
    float nrm = dinv[r] * ew[e] * dinv[c];
    int pos = atomicAdd(&head[c], 1);
    csr[pos] = ((ull)__float_as_uint(nrm) << 32) | (unsigned)r;
}

__global__ __launch_bounds__(256) void fill_self_kernel(const float* __restrict__ dinv,
                                                        int* __restrict__ head,
                                                        ull* __restrict__ csr, int N) {
    int c = blockIdx.x * 256 + threadIdx.x;
    if (c >= N) return;
    float d = dinv[c];
    int pos = atomicAdd(&head[c], 1);
    csr[pos] = ((ull)__float_as_uint(d * d) << 32) | (unsigned)c;
}

// ---------- GEMM1: h = x @ W1   [N,512]@[512,16] ----------
__global__ __launch_bounds__(256) void gemm1_kernel(const float* __restrict__ x,
                                                    const float* __restrict__ W1,
                                                    float* __restrict__ h, int N) {
    __shared__ float w1s[NF1 * 516];
    int tid = threadIdx.x;
    for (int idx = tid; idx < FIN * NF1; idx += 256) {
        int k = idx >> 4, f = idx & 15;
        w1s[f * 516 + k] = W1[idx];
    }
    __syncthreads();

    int r = tid >> 4, f = tid & 15;
    int row = blockIdx.x * 16 + r;
    if (row >= N) return;
    const float* xr = x + (size_t)row * FIN;
    const float* wf = w1s + f * 516;
    float acc = 0.0f;
#pragma unroll 4
    for (int k = 0; k < FIN; k += 4) {
        float4 xv = *reinterpret_cast<const float4*>(xr + k);
        float4 wv = *reinterpret_cast<const float4*>(wf + k);
        acc += xv.x * wv.x + xv.y * wv.y + xv.z * wv.z + xv.w * wv.w;
    }
    h[(size_t)row * NF1 + f] = acc;
}

// ---------- gather layer 1: x1[c] = b1 + sum_{(r,w) in csr[c]} w * h[r]  ----------
__global__ __launch_bounds__(256) void gather1_kernel(const ull* __restrict__ csr,
                                                      const int* __restrict__ rowptr,
                                                      const float* __restrict__ h,
                                                      const float* __restrict__ b1,
                                                      float* __restrict__ x1, int N) {
    int t = blockIdx.x * 256 + threadIdx.x;
    int node = t >> 4, f = t & 15;
    if (node >= N) return;
    int s = rowptr[node], e = rowptr[node + 1];
    float acc = b1[f];
    int i = s;
    for (; i + 1 < e; i += 2) {
        ull v0 = csr[i], v1 = csr[i + 1];
        int r0 = (int)(v0 & 0xffffffffull); float w0 = __uint_as_float((unsigned)(v0 >> 32));
        int r1 = (int)(v1 & 0xffffffffull); float w1 = __uint_as_float((unsigned)(v1 >> 32));
        acc += w0 * h[(size_t)r0 * NF1 + f];
        acc += w1 * h[(size_t)r1 * NF1 + f];
    }
    if (i < e) {
        ull v = csr[i];
        int r = (int)(v & 0xffffffffull); float w = __uint_as_float((unsigned)(v >> 32));
        acc += w * h[(size_t)r * NF1 + f];
    }
    x1[(size_t)node * NF1 + f] = acc;
}

// ---------- GEMM2: hh = relu(x1) @ W2   [N,16]@[16,10] ----------
__global__ __launch_bounds__(256) void gemm2_kernel(const float* __restrict__ x1,
                                                    const float* __restrict__ W2,
                                                    float* __restrict__ hh, int N) {
    int j = blockIdx.x * 256 + threadIdx.x;
    if (j >= N) return;
    float xr[NF1];
#pragma unroll
    for (int f = 0; f < NF1; f++) xr[f] = fmaxf(x1[(size_t)j * NF1 + f], 0.0f);
#pragma unroll
    for (int c = 0; c < NF2; c++) {
        float acc = 0.0f;
#pragma unroll
        for (int f = 0; f < NF1; f++) acc += xr[f] * W2[f * NF2 + c];
        hh[(size_t)j * NF2 + c] = acc;
    }
}

// ---------- gather layer 2 + fused log-softmax ----------
__global__ __launch_bounds__(256) void gather2_lsm_kernel(const ull* __restrict__ csr,
                                                          const int* __restrict__ rowptr,
                                                          const float* __restrict__ hh,
                                                          const float* __restrict__ b2,
                                                          float* __restrict__ out, int N) {
    int t = blockIdx.x * 256 + threadIdx.x;
    int node = t >> 4, f = t & 15;
    bool act = (node < N) && (f < NF2);
    float acc = act ? b2[f] : 0.0f;
    if (node < N) {
        int s = rowptr[node], e = rowptr[node + 1];
        int i = s;
        for (; i + 1 < e; i += 2) {
            ull v0 = csr[i], v1 = csr[i + 1];
            int r0 = (int)(v0 & 0xffffffffull); float w0 = __uint_as_float((unsigned)(v0 >> 32));
            int r1 = (int)(v1 & 0xffffffffull); float w1 = __uint_as_float((unsigned)(v1 >> 32));
            float h0 = (f < NF2) ? hh[(size_t)r0 * NF2 + f] : 0.0f;
            float h1 = (f < NF2) ? hh[(size_t)r1 * NF2 + f] : 0.0f;
            acc += w0 * h0 + w1 * h1;
        }
        if (i < e) {
            ull v = csr[i];
            int r = (int)(v & 0xffffffffull); float w = __uint_as_float((unsigned)(v >> 32));
            float hv = (f < NF2) ? hh[(size_t)r * NF2 + f] : 0.0f;
            acc += w * hv;
        }
    }
    // log-softmax across the 16-lane group (10 active lanes)
    float m = act ? acc : -INFINITY;
#pragma unroll
    for (int off = 1; off < 16; off <<= 1) m = fmaxf(m, __shfl_xor(m, off, 16));
    float p = act ? expf(acc - m) : 0.0f;
    float ssum = p;
#pragma unroll
    for (int off = 1; off < 16; off <<= 1) ssum += __shfl_xor(ssum, off, 16);
    if (act) out[(size_t)node * NF2 + f] = acc - m - logf(ssum);
}

extern "C" void kernel_launch(void* const* d_in, const int* in_sizes, int n_in,
                              void* d_out, int out_size, void* d_ws, size_t ws_size,
                              hipStream_t stream) {
    const float* x  = (const float*)d_in[0];
    const int*   ei = (const int*)d_in[1];
    const float* ew = (const float*)d_in[2];
    const float* W1 = (const float*)d_in[3];
    const float* b1 = (const float*)d_in[4];
    const float* W2 = (const float*)d_in[5];
    const float* b2 = (const float*)d_in[6];

    const int E = in_sizes[2];           // 3,200,000
    const int N = in_sizes[0] / FIN;     // 100,000
    const int* row = ei;
    const int* col = ei + E;

    float* out    = (float*)d_out;
    float* logits = out;                        // [N,10]
    float* x1     = out + (size_t)N * NF2;      // [N,16]

    char* ws = (char*)d_ws;
    size_t off = 0;
    auto alloc = [&](size_t bytes) { void* p = ws + off; off += (bytes + 255) / 256 * 256; return p; };
    float* h      = (float*)alloc((size_t)N * NF1 * 4);
    float* hh     = (float*)alloc((size_t)N * NF2 * 4 + 64);
    float* deg    = (float*)alloc((size_t)N * 4);          // becomes dinv in place
    int*   cnt    = (int*)  alloc((size_t)N * 4);
    int*   rowptr = (int*)  alloc((size_t)(N + 1) * 4);
    int*   head   = (int*)  alloc((size_t)N * 4);
    int*   part   = (int*)  alloc(1024 * 4);
    ull*   csr    = (ull*)  alloc((size_t)(E + N) * 8);
    (void)ws_size; (void)n_in; (void)out_size;

    dim3 blk(256);
    int gN  = (N + 255) / 256;    // node-grid (1 thread/node)
    int gE  = (E + 255) / 256;
    int g16 = (N + 15) / 16;      // node-grid (16 threads/node)
    int nb  = gN;                 // scan blocks (<=1024 assumed; N<=262144)

    // degree + counts (self-loop pre-counted)
    init_deg_cnt_kernel<<<gN, blk, 0, stream>>>(deg, cnt, N);
    edge_count_kernel<<<gE, blk, 0, stream>>>(col, ew, deg, cnt, E);
    dinv_kernel<<<gN, blk, 0, stream>>>(deg, N);

    // rowptr = exclusive_scan(cnt); head = rowptr
    block_sum_kernel<<<nb, blk, 0, stream>>>(cnt, part, N);
    part_scan_kernel<<<1, 1024, 0, stream>>>(part, nb);
    scan_apply_kernel<<<nb, blk, 0, stream>>>(cnt, part, rowptr, head, N, E + N);

    // CSR fill with packed (norm, src)
    fill_edges_kernel<<<gE, blk, 0, stream>>>(row, col, ew, deg, head, csr, E);
    fill_self_kernel<<<gN, blk, 0, stream>>>(deg, head, csr, N);

    // layer 1: dense GEMM then gather-aggregate
    gemm1_kernel<<<g16, blk, 0, stream>>>(x, W1, h, N);
    gather1_kernel<<<g16, blk, 0, stream>>>(csr, rowptr, h, b1, x1, N);

    // layer 2: small GEMM then gather-aggregate + fused log-softmax
    gemm2_kernel<<<gN, blk, 0, stream>>>(x1, W2, hh, N);
    gather2_lsm_kernel<<<g16, blk, 0, stream>>>(csr, rowptr, hh, b2, logits, N);
}

// Round 3
// 584.152 us; speedup vs baseline: 1.2808x; 1.2808x over previous
//
#include <hip/hip_runtime.h>
#include <hip/hip_bf16.h>

// GCN 2-layer forward on MI355X — CSR via two-level LDS counting sort
// (zero global atomics; device-scope atomics cost ~23G line-touches/s on
//  gfx950 due to cross-XCD write-through, measured round 2).
// Inputs: x[N,512] f32, edge_index[2,E] int32, edge_weight[E] f32,
//         W1[512,16], b1[16], W2[16,10], b2[10]
// Outputs (concat): log_softmax(logits)[N,10], x1[N,16]

#define NF1 16   // hidden
#define NF2 10   // classes
#define FIN 512
#define EPB 8192 // edges per coarse block (256 thr * 32)

typedef unsigned long long ull;

// ---------- A: coarse count (col>>9) into per-block histograms ----------
// blkhist layout TRANSPOSED: blkhist[bucket*NBLK + blk] so pass B scans
// contiguously per bucket.
__global__ __launch_bounds__(256) void coarse_count_kernel(const int* __restrict__ col,
                                                           int* __restrict__ blkhist,
                                                           int E, int NB, int NBLK) {
    __shared__ int lh[256];
    int t = threadIdx.x;
    lh[t] = 0;
    __syncthreads();
    int base = blockIdx.x * EPB;
    int cnt = min(EPB, E - base);
    for (int i = t; i < cnt; i += 256)
        atomicAdd(&lh[col[base + i] >> 9], 1);
    __syncthreads();
    if (t < NB) blkhist[t * NBLK + blockIdx.x] = lh[t];
}

// ---------- B: scan per-bucket over blocks -> absolute cursors ----------
__global__ __launch_bounds__(256) void scan_offsets_kernel(int* __restrict__ blkhist,
                                                           int* __restrict__ bbase,
                                                           int* __restrict__ rowptr,
                                                           int NBLK, int NB, int E, int N) {
    __shared__ int s[256];
    int t = threadIdx.x;
    int total = 0;
    if (t < NB) {
        int* p = blkhist + (size_t)t * NBLK;
        for (int k = 0; k < NBLK; k++) {   // within-bucket exclusive prefix
            int v = p[k];
            p[k] = total;
            total += v;
        }
    }
    s[t] = (t < NB) ? total : 0;
    __syncthreads();
    for (int off = 1; off < 256; off <<= 1) {  // inclusive scan of totals
        int v = (t >= off) ? s[t - off] : 0;
        __syncthreads();
        s[t] += v;
        __syncthreads();
    }
    int excl = s[t] - ((t < NB) ? total : 0);
    if (t < NB) {
        bbase[t] = excl;
        int* p = blkhist + (size_t)t * NBLK;
        for (int k = 0; k < NBLK; k++) p[k] += excl;
    }
    if (t == 0) { bbase[NB] = E; rowptr[N] = E; }
}

// ---------- C: coarse scatter into bucket-ordered pool ----------
// pool entry: hi32 = (c9<<20)|row, lo32 = weight bits
__global__ __launch_bounds__(256) void coarse_scatter_kernel(const int* __restrict__ row,
                                                             const int* __restrict__ col,
                                                             const float* __restrict__ ew,
                                                             const int* __restrict__ blkhist,
                                                             ull* __restrict__ pool,
                                                             int E, int NB, int NBLK) {
    __shared__ int cur[256];
    int t = threadIdx.x;
    if (t < NB) cur[t] = blkhist[t * NBLK + blockIdx.x];
    __syncthreads();
    int base = blockIdx.x * EPB;
    int cnt = min(EPB, E - base);
    for (int i = t; i < cnt; i += 256) {
        int e = base + i;
        int c = col[e], r = row[e];
        float w = ew[e];
        int b = c >> 9, c9 = c & 511;
        int pos = atomicAdd(&cur[b], 1);
        pool[pos] = ((ull)((((unsigned)c9) << 20) | (unsigned)r) << 32) | (ull)__float_as_uint(w);
    }
}

// ---------- D: fine sort within bucket (512 cols) -> CSR, rowptr, dinv ----------
// csr entry: hi32 = weight bits, lo32 = src row
__global__ __launch_bounds__(1024) void fine_sort_kernel(const ull* __restrict__ pool,
                                                         const int* __restrict__ bbase,
                                                         ull* __restrict__ csr,
                                                         int* __restrict__ rowptr,
                                                         float* __restrict__ dinv, int N) {
    __shared__ int hist[512];
    __shared__ float wsum[512];
    __shared__ int cur[512];
    int t = threadIdx.x;
    int b = blockIdx.x;
    int bb = bbase[b], be = bbase[b + 1];
    int Ki = be - bb;
    if (t < 512) { hist[t] = 0; wsum[t] = 0.0f; }
    __syncthreads();
    for (int i = t; i < Ki; i += 1024) {
        ull p = pool[bb + i];
        unsigned hi = (unsigned)(p >> 32);
        int c9 = (hi >> 20) & 511;
        atomicAdd(&hist[c9], 1);
        atomicAdd(&wsum[c9], __uint_as_float((unsigned)p));
    }
    __syncthreads();
    int own = (t < 512) ? hist[t] : 0;
    if (t < 512) cur[t] = own;
    __syncthreads();
    for (int off = 1; off < 512; off <<= 1) {   // inclusive scan
        int v = (t >= off && t < 512) ? cur[t - off] : 0;
        __syncthreads();
        if (t < 512) cur[t] += v;
        __syncthreads();
    }
    int excl = (t < 512) ? (cur[t] - own) : 0;
    if (t < 512) cur[t] = excl;                 // own-cell only: no race
    int c = (b << 9) + t;
    if (t < 512 && c < N) {
        rowptr[c] = bb + excl;
        dinv[c] = rsqrtf(1.0f + wsum[t]);       // deg = self(1) + sum(w) >= 1
    }
    __syncthreads();
    for (int i = t; i < Ki; i += 1024) {        // place (pool range is L2-hot)
        ull p = pool[bb + i];
        unsigned hi = (unsigned)(p >> 32);
        int c9 = (hi >> 20) & 511;
        unsigned r = hi & 0xFFFFFu;
        int k = atomicAdd(&cur[c9], 1);
        csr[bb + k] = ((p & 0xFFFFFFFFull) << 32) | (ull)r;
    }
}

// ---------- F: fold dinv[row] into stored weight ----------
__global__ __launch_bounds__(256) void norm_xform_kernel(ull* __restrict__ csr,
                                                         const float* __restrict__ dinv, int E) {
    int i = blockIdx.x * 256 + threadIdx.x;
    if (i >= E) return;
    ull v = csr[i];
    unsigned r = (unsigned)v;
    float w = __uint_as_float((unsigned)(v >> 32)) * dinv[r];
    csr[i] = ((ull)__float_as_uint(w) << 32) | (ull)r;
}

// ---------- GEMM1: h = x @ W1   [N,512]@[512,16] ----------
__global__ __launch_bounds__(256) void gemm1_kernel(const float* __restrict__ x,
                                                    const float* __restrict__ W1,
                                                    float* __restrict__ h, int N) {
    __shared__ float w1s[NF1 * 516];
    int tid = threadIdx.x;
    for (int idx = tid; idx < FIN * NF1; idx += 256) {
        int k = idx >> 4, f = idx & 15;
        w1s[f * 516 + k] = W1[idx];
    }
    __syncthreads();

    int r = tid >> 4, f = tid & 15;
    int row = blockIdx.x * 16 + r;
    if (row >= N) return;
    const float* xr = x + (size_t)row * FIN;
    const float* wf = w1s + f * 516;
    float acc = 0.0f;
#pragma unroll 4
    for (int k = 0; k < FIN; k += 4) {
        float4 xv = *reinterpret_cast<const float4*>(xr + k);
        float4 wv = *reinterpret_cast<const float4*>(wf + k);
        acc += xv.x * wv.x + xv.y * wv.y + xv.z * wv.z + xv.w * wv.w;
    }
    h[(size_t)row * NF1 + f] = acc;
}

// ---------- gather layer 1: x1[c] = b1 + dinv[c]*(sum s_i*h[r_i] + dinv[c]*h[c]) ----------
__global__ __launch_bounds__(256) void gather1_kernel(const ull* __restrict__ csr,
                                                      const int* __restrict__ rowptr,
                                                      const float* __restrict__ dinv,
                                                      const float* __restrict__ h,
                                                      const float* __restrict__ b1,
                                                      float* __restrict__ x1, int N) {
    int t = blockIdx.x * 256 + threadIdx.x;
    int node = t >> 4, f = t & 15;
    if (node >= N) return;
    int s = rowptr[node], e = rowptr[node + 1];
    float di = dinv[node];
    float acc = di * h[(size_t)node * NF1 + f];   // self-loop term (w=1)
    int i = s;
    for (; i + 1 < e; i += 2) {
        ull v0 = csr[i], v1 = csr[i + 1];
        int r0 = (int)(v0 & 0xffffffffull); float w0 = __uint_as_float((unsigned)(v0 >> 32));
        int r1 = (int)(v1 & 0xffffffffull); float w1 = __uint_as_float((unsigned)(v1 >> 32));
        acc += w0 * h[(size_t)r0 * NF1 + f];
        acc += w1 * h[(size_t)r1 * NF1 + f];
    }
    if (i < e) {
        ull v = csr[i];
        int r = (int)(v & 0xffffffffull); float w = __uint_as_float((unsigned)(v >> 32));
        acc += w * h[(size_t)r * NF1 + f];
    }
    x1[(size_t)node * NF1 + f] = b1[f] + di * acc;
}

// ---------- GEMM2: hh = relu(x1) @ W2   [N,16]@[16,10] ----------
__global__ __launch_bounds__(256) void gemm2_kernel(const float* __restrict__ x1,
                                                    const float* __restrict__ W2,
                                                    float* __restrict__ hh, int N) {
    int j = blockIdx.x * 256 + threadIdx.x;
    if (j >= N) return;
    float xr[NF1];
#pragma unroll
    for (int f = 0; f < NF1; f++) xr[f] = fmaxf(x1[(size_t)j * NF1 + f], 0.0f);
#pragma unroll
    for (int c = 0; c < NF2; c++) {
        float acc = 0.0f;
#pragma unroll
        for (int f = 0; f < NF1; f++) acc += xr[f] * W2[f * NF2 + c];
        hh[(size_t)j * NF2 + c] = acc;
    }
}

// ---------- gather layer 2 + fused log-softmax ----------
__global__ __launch_bounds__(256) void gather2_lsm_kernel(const ull* __restrict__ csr,
                                                          const int* __restrict__ rowptr,
                                                          const float* __restrict__ dinv,
                                                          const float* __restrict__ hh,
                                                          const float* __restrict__ b2,
                                                          float* __restrict__ out, int N) {
    int t = blockIdx.x * 256 + threadIdx.x;
    int node = t >> 4, f = t & 15;
    bool act = (node < N) && (f < NF2);
    float acc = 0.0f;
    if (node < N) {
        int s = rowptr[node], e = rowptr[node + 1];
        float di = dinv[node];
        acc = act ? di * hh[(size_t)node * NF2 + f] : 0.0f;  // self-loop term
        int i = s;
        for (; i + 1 < e; i += 2) {
            ull v0 = csr[i], v1 = csr[i + 1];
            int r0 = (int)(v0 & 0xffffffffull); float w0 = __uint_as_float((unsigned)(v0 >> 32));
            int r1 = (int)(v1 & 0xffffffffull); float w1 = __uint_as_float((unsigned)(v1 >> 32));
            float h0 = (f < NF2) ? hh[(size_t)r0 * NF2 + f] : 0.0f;
            float h1 = (f < NF2) ? hh[(size_t)r1 * NF2 + f] : 0.0f;
            acc += w0 * h0 + w1 * h1;
        }
        if (i < e) {
            ull v = csr[i];
            int r = (int)(v & 0xffffffffull); float w = __uint_as_float((unsigned)(v >> 32));
            float hv = (f < NF2) ? hh[(size_t)r * NF2 + f] : 0.0f;
            acc += w * hv;
        }
        acc = b2[f] + di * acc;  // logits (garbage in lanes f>=10, masked below)
    }
    // log-softmax across the 16-lane group (10 active lanes)
    float m = act ? acc : -INFINITY;
#pragma unroll
    for (int off = 1; off < 16; off <<= 1) m = fmaxf(m, __shfl_xor(m, off, 16));
    float p = act ? expf(acc - m) : 0.0f;
    float ssum = p;
#pragma unroll
    for (int off = 1; off < 16; off <<= 1) ssum += __shfl_xor(ssum, off, 16);
    if (act) out[(size_t)node * NF2 + f] = acc - m - logf(ssum);
}

extern "C" void kernel_launch(void* const* d_in, const int* in_sizes, int n_in,
                              void* d_out, int out_size, void* d_ws, size_t ws_size,
                              hipStream_t stream) {
    const float* x  = (const float*)d_in[0];
    const int*   ei = (const int*)d_in[1];
    const float* ew = (const float*)d_in[2];
    const float* W1 = (const float*)d_in[3];
    const float* b1 = (const float*)d_in[4];
    const float* W2 = (const float*)d_in[5];
    const float* b2 = (const float*)d_in[6];

    const int E = in_sizes[2];           // 3,200,000
    const int N = in_sizes[0] / FIN;     // 100,000
    const int* row = ei;
    const int* col = ei + E;

    const int NB   = (N + 511) >> 9;     // coarse buckets (196)
    const int NBLK = (E + EPB - 1) / EPB;

    float* out    = (float*)d_out;
    float* logits = out;                        // [N,10]
    float* x1     = out + (size_t)N * NF2;      // [N,16]

    char* ws = (char*)d_ws;
    size_t off = 0;
    auto alloc = [&](size_t bytes) { void* p = ws + off; off += (bytes + 255) / 256 * 256; return p; };
    ull*   pool    = (ull*)  alloc((size_t)E * 8);
    ull*   csr     = (ull*)  alloc((size_t)E * 8);
    float* h       = (float*)alloc((size_t)N * NF1 * 4);
    float* hh      = (float*)alloc((size_t)N * NF2 * 4 + 64);
    float* dinv    = (float*)alloc((size_t)N * 4);
    int*   rowptr  = (int*)  alloc((size_t)(N + 1) * 4);
    int*   blkhist = (int*)  alloc((size_t)NB * NBLK * 4);
    int*   bbase   = (int*)  alloc((size_t)(NB + 1) * 4);
    (void)ws_size; (void)n_in; (void)out_size;

    dim3 blk(256);
    int gN  = (N + 255) / 256;
    int gE  = (E + 255) / 256;
    int g16 = (N + 15) / 16;

    // build CSR (no global atomics)
    coarse_count_kernel<<<NBLK, blk, 0, stream>>>(col, blkhist, E, NB, NBLK);
    scan_offsets_kernel<<<1, blk, 0, stream>>>(blkhist, bbase, rowptr, NBLK, NB, E, N);
    coarse_scatter_kernel<<<NBLK, blk, 0, stream>>>(row, col, ew, blkhist, pool, E, NB, NBLK);
    fine_sort_kernel<<<NB, dim3(1024), 0, stream>>>(pool, bbase, csr, rowptr, dinv, N);
    norm_xform_kernel<<<gE, blk, 0, stream>>>(csr, dinv, E);

    // layer 1
    gemm1_kernel<<<g16, blk, 0, stream>>>(x, W1, h, N);
    gather1_kernel<<<g16, blk, 0, stream>>>(csr, rowptr, dinv, h, b1, x1, N);

    // layer 2
    gemm2_kernel<<<gN, blk, 0, stream>>>(x1, W2, hh, N);
    gather2_lsm_kernel<<<g16, blk, 0, stream>>>(csr, rowptr, dinv, hh, b2, logits, N);
}

// Round 4
// 403.733 us; speedup vs baseline: 1.8531x; 1.4469x over previous
//
#include <hip/hip_runtime.h>
#include <hip/hip_bf16.h>

// GCN 2-layer forward on MI355X — CSR via two-level LDS counting sort
// (zero global atomics). Round-4 change: the serial 1-block offset scan
// (186 us, latency-bound) is replaced by a parallel per-bucket scan.
// Inputs: x[N,512] f32, edge_index[2,E] int32, edge_weight[E] f32,
//         W1[512,16], b1[16], W2[16,10], b2[10]
// Outputs (concat): log_softmax(logits)[N,10], x1[N,16]

#define NF1 16   // hidden
#define NF2 10   // classes
#define FIN 512
#define EPB 8192 // edges per coarse block (256 thr * 32)

typedef unsigned long long ull;

// ---------- A: coarse count (col>>9) into per-block histograms ----------
// blkhist layout TRANSPOSED: blkhist[bucket*NBLK + blk] so the per-bucket
// scan reads contiguously.
__global__ __launch_bounds__(256) void coarse_count_kernel(const int* __restrict__ col,
                                                           int* __restrict__ blkhist,
                                                           int E, int NB, int NBLK) {
    __shared__ int lh[256];
    int t = threadIdx.x;
    lh[t] = 0;
    __syncthreads();
    int base = blockIdx.x * EPB;
    int cnt = min(EPB, E - base);
    for (int i = t; i < cnt; i += 256)
        atomicAdd(&lh[col[base + i] >> 9], 1);
    __syncthreads();
    if (t < NB) blkhist[t * NBLK + blockIdx.x] = lh[t];
}

// ---------- B1: per-bucket exclusive scan over blocks (parallel) ----------
__global__ __launch_bounds__(512) void bucket_scan_kernel(int* __restrict__ blkhist,
                                                          int* __restrict__ btot,
                                                          int NBLK) {
    __shared__ int s[512];
    int t = threadIdx.x;
    int* p = blkhist + (size_t)blockIdx.x * NBLK;
    int carry = 0;
    for (int base = 0; base < NBLK; base += 512) {
        int idx = base + t;
        int v = (idx < NBLK) ? p[idx] : 0;
        s[t] = v;
        __syncthreads();
        for (int off = 1; off < 512; off <<= 1) {   // inclusive Hillis-Steele
            int u = (t >= off) ? s[t - off] : 0;
            __syncthreads();
            s[t] += u;
            __syncthreads();
        }
        if (idx < NBLK) p[idx] = s[t] - v + carry;  // exclusive within bucket
        carry += s[511];
        __syncthreads();
    }
    if (t == 0) btot[blockIdx.x] = carry;
}

// ---------- B2: scan bucket totals -> bbase ----------
__global__ __launch_bounds__(256) void base_scan_kernel(const int* __restrict__ btot,
                                                        int* __restrict__ bbase,
                                                        int* __restrict__ rowptr,
                                                        int NB, int E, int N) {
    __shared__ int s[256];
    int t = threadIdx.x;
    int v = (t < NB) ? btot[t] : 0;
    s[t] = v;
    __syncthreads();
    for (int off = 1; off < 256; off <<= 1) {
        int u = (t >= off) ? s[t - off] : 0;
        __syncthreads();
        s[t] += u;
        __syncthreads();
    }
    if (t < NB) bbase[t] = s[t] - v;
    if (t == 0) { bbase[NB] = E; rowptr[N] = E; }
}

// ---------- C: coarse scatter into bucket-ordered pool ----------
// pool entry: hi32 = (c9<<20)|row, lo32 = weight bits
__global__ __launch_bounds__(256) void coarse_scatter_kernel(const int* __restrict__ row,
                                                             const int* __restrict__ col,
                                                             const float* __restrict__ ew,
                                                             const int* __restrict__ blkhist,
                                                             const int* __restrict__ bbase,
                                                             ull* __restrict__ pool,
                                                             int E, int NB, int NBLK) {
    __shared__ int cur[256];
    int t = threadIdx.x;
    if (t < NB) cur[t] = blkhist[t * NBLK + blockIdx.x] + bbase[t];
    __syncthreads();
    int base = blockIdx.x * EPB;
    int cnt = min(EPB, E - base);
    for (int i = t; i < cnt; i += 256) {
        int e = base + i;
        int c = col[e], r = row[e];
        float w = ew[e];
        int b = c >> 9, c9 = c & 511;
        int pos = atomicAdd(&cur[b], 1);
        pool[pos] = ((ull)((((unsigned)c9) << 20) | (unsigned)r) << 32) | (ull)__float_as_uint(w);
    }
}

// ---------- D: fine sort within bucket (512 cols) -> CSR, rowptr, dinv ----------
// csr entry: hi32 = weight bits, lo32 = src row
__global__ __launch_bounds__(1024) void fine_sort_kernel(const ull* __restrict__ pool,
                                                         const int* __restrict__ bbase,
                                                         ull* __restrict__ csr,
                                                         int* __restrict__ rowptr,
                                                         float* __restrict__ dinv, int N) {
    __shared__ int hist[512];
    __shared__ float wsum[512];
    __shared__ int cur[512];
    int t = threadIdx.x;
    int b = blockIdx.x;
    int bb = bbase[b], be = bbase[b + 1];
    int Ki = be - bb;
    if (t < 512) { hist[t] = 0; wsum[t] = 0.0f; }
    __syncthreads();
    for (int i = t; i < Ki; i += 1024) {
        ull p = pool[bb + i];
        unsigned hi = (unsigned)(p >> 32);
        int c9 = (hi >> 20) & 511;
        atomicAdd(&hist[c9], 1);
        atomicAdd(&wsum[c9], __uint_as_float((unsigned)p));
    }
    __syncthreads();
    int own = (t < 512) ? hist[t] : 0;
    if (t < 512) cur[t] = own;
    __syncthreads();
    for (int off = 1; off < 512; off <<= 1) {   // inclusive scan
        int v = (t >= off && t < 512) ? cur[t - off] : 0;
        __syncthreads();
        if (t < 512) cur[t] += v;
        __syncthreads();
    }
    int excl = (t < 512) ? (cur[t] - own) : 0;
    if (t < 512) cur[t] = excl;                 // own-cell only: no race
    int c = (b << 9) + t;
    if (t < 512 && c < N) {
        rowptr[c] = bb + excl;
        dinv[c] = rsqrtf(1.0f + wsum[t]);       // deg = self(1) + sum(w) >= 1
    }
    __syncthreads();
    for (int i = t; i < Ki; i += 1024) {        // place (pool range is L2-hot)
        ull p = pool[bb + i];
        unsigned hi = (unsigned)(p >> 32);
        int c9 = (hi >> 20) & 511;
        unsigned r = hi & 0xFFFFFu;
        int k = atomicAdd(&cur[c9], 1);
        csr[bb + k] = ((p & 0xFFFFFFFFull) << 32) | (ull)r;
    }
}

// ---------- F: fold dinv[row] into stored weight ----------
__global__ __launch_bounds__(256) void norm_xform_kernel(ull* __restrict__ csr,
                                                         const float* __restrict__ dinv, int E) {
    int i = blockIdx.x * 256 + threadIdx.x;
    if (i >= E) return;
    ull v = csr[i];
    unsigned r = (unsigned)v;
    float w = __uint_as_float((unsigned)(v >> 32)) * dinv[r];
    csr[i] = ((ull)__float_as_uint(w) << 32) | (ull)r;
}

// ---------- GEMM1: h = x @ W1   [N,512]@[512,16] ----------
__global__ __launch_bounds__(256) void gemm1_kernel(const float* __restrict__ x,
                                                    const float* __restrict__ W1,
                                                    float* __restrict__ h, int N) {
    __shared__ float w1s[NF1 * 516];
    int tid = threadIdx.x;
    for (int idx = tid; idx < FIN * NF1; idx += 256) {
        int k = idx >> 4, f = idx & 15;
        w1s[f * 516 + k] = W1[idx];
    }
    __syncthreads();

    int r = tid >> 4, f = tid & 15;
    int row = blockIdx.x * 16 + r;
    if (row >= N) return;
    const float* xr = x + (size_t)row * FIN;
    const float* wf = w1s + f * 516;
    float acc = 0.0f;
#pragma unroll 4
    for (int k = 0; k < FIN; k += 4) {
        float4 xv = *reinterpret_cast<const float4*>(xr + k);
        float4 wv = *reinterpret_cast<const float4*>(wf + k);
        acc += xv.x * wv.x + xv.y * wv.y + xv.z * wv.z + xv.w * wv.w;
    }
    h[(size_t)row * NF1 + f] = acc;
}

// ---------- gather layer 1: x1[c] = b1 + dinv[c]*(sum s_i*h[r_i] + dinv[c]*h[c]) ----------
__global__ __launch_bounds__(256) void gather1_kernel(const ull* __restrict__ csr,
                                                      const int* __restrict__ rowptr,
                                                      const float* __restrict__ dinv,
                                                      const float* __restrict__ h,
                                                      const float* __restrict__ b1,
                                                      float* __restrict__ x1, int N) {
    int t = blockIdx.x * 256 + threadIdx.x;
    int node = t >> 4, f = t & 15;
    if (node >= N) return;
    int s = rowptr[node], e = rowptr[node + 1];
    float di = dinv[node];
    float acc = di * h[(size_t)node * NF1 + f];   // self-loop term (w=1)
    int i = s;
    for (; i + 1 < e; i += 2) {
        ull v0 = csr[i], v1 = csr[i + 1];
        int r0 = (int)(v0 & 0xffffffffull); float w0 = __uint_as_float((unsigned)(v0 >> 32));
        int r1 = (int)(v1 & 0xffffffffull); float w1 = __uint_as_float((unsigned)(v1 >> 32));
        acc += w0 * h[(size_t)r0 * NF1 + f];
        acc += w1 * h[(size_t)r1 * NF1 + f];
    }
    if (i < e) {
        ull v = csr[i];
        int r = (int)(v & 0xffffffffull); float w = __uint_as_float((unsigned)(v >> 32));
        acc += w * h[(size_t)r * NF1 + f];
    }
    x1[(size_t)node * NF1 + f] = b1[f] + di * acc;
}

// ---------- GEMM2: hh = relu(x1) @ W2   [N,16]@[16,10] ----------
__global__ __launch_bounds__(256) void gemm2_kernel(const float* __restrict__ x1,
                                                    const float* __restrict__ W2,
                                                    float* __restrict__ hh, int N) {
    int j = blockIdx.x * 256 + threadIdx.x;
    if (j >= N) return;
    float xr[NF1];
#pragma unroll
    for (int f = 0; f < NF1; f++) xr[f] = fmaxf(x1[(size_t)j * NF1 + f], 0.0f);
#pragma unroll
    for (int c = 0; c < NF2; c++) {
        float acc = 0.0f;
#pragma unroll
        for (int f = 0; f < NF1; f++) acc += xr[f] * W2[f * NF2 + c];
        hh[(size_t)j * NF2 + c] = acc;
    }
}

// ---------- gather layer 2 + fused log-softmax ----------
__global__ __launch_bounds__(256) void gather2_lsm_kernel(const ull* __restrict__ csr,
                                                          const int* __restrict__ rowptr,
                                                          const float* __restrict__ dinv,
                                                          const float* __restrict__ hh,
                                                          const float* __restrict__ b2,
                                                          float* __restrict__ out, int N) {
    int t = blockIdx.x * 256 + threadIdx.x;
    int node = t >> 4, f = t & 15;
    bool act = (node < N) && (f < NF2);
    float acc = 0.0f;
    if (node < N) {
        int s = rowptr[node], e = rowptr[node + 1];
        float di = dinv[node];
        acc = act ? di * hh[(size_t)node * NF2 + f] : 0.0f;  // self-loop term
        int i = s;
        for (; i + 1 < e; i += 2) {
            ull v0 = csr[i], v1 = csr[i + 1];
            int r0 = (int)(v0 & 0xffffffffull); float w0 = __uint_as_float((unsigned)(v0 >> 32));
            int r1 = (int)(v1 & 0xffffffffull); float w1 = __uint_as_float((unsigned)(v1 >> 32));
            float h0 = (f < NF2) ? hh[(size_t)r0 * NF2 + f] : 0.0f;
            float h1 = (f < NF2) ? hh[(size_t)r1 * NF2 + f] : 0.0f;
            acc += w0 * h0 + w1 * h1;
        }
        if (i < e) {
            ull v = csr[i];
            int r = (int)(v & 0xffffffffull); float w = __uint_as_float((unsigned)(v >> 32));
            float hv = (f < NF2) ? hh[(size_t)r * NF2 + f] : 0.0f;
            acc += w * hv;
        }
        acc = b2[f] + di * acc;  // logits (garbage in lanes f>=10, masked below)
    }
    // log-softmax across the 16-lane group (10 active lanes)
    float m = act ? acc : -INFINITY;
#pragma unroll
    for (int off = 1; off < 16; off <<= 1) m = fmaxf(m, __shfl_xor(m, off, 16));
    float p = act ? expf(acc - m) : 0.0f;
    float ssum = p;
#pragma unroll
    for (int off = 1; off < 16; off <<= 1) ssum += __shfl_xor(ssum, off, 16);
    if (act) out[(size_t)node * NF2 + f] = acc - m - logf(ssum);
}

extern "C" void kernel_launch(void* const* d_in, const int* in_sizes, int n_in,
                              void* d_out, int out_size, void* d_ws, size_t ws_size,
                              hipStream_t stream) {
    const float* x  = (const float*)d_in[0];
    const int*   ei = (const int*)d_in[1];
    const float* ew = (const float*)d_in[2];
    const float* W1 = (const float*)d_in[3];
    const float* b1 = (const float*)d_in[4];
    const float* W2 = (const float*)d_in[5];
    const float* b2 = (const float*)d_in[6];

    const int E = in_sizes[2];           // 3,200,000
    const int N = in_sizes[0] / FIN;     // 100,000
    const int* row = ei;
    const int* col = ei + E;

    const int NB   = (N + 511) >> 9;     // coarse buckets (196)
    const int NBLK = (E + EPB - 1) / EPB;

    float* out    = (float*)d_out;
    float* logits = out;                        // [N,10]
    float* x1     = out + (size_t)N * NF2;      // [N,16]

    char* ws = (char*)d_ws;
    size_t off = 0;
    auto alloc = [&](size_t bytes) { void* p = ws + off; off += (bytes + 255) / 256 * 256; return p; };
    ull*   pool    = (ull*)  alloc((size_t)E * 8);
    ull*   csr     = (ull*)  alloc((size_t)E * 8);
    float* h       = (float*)alloc((size_t)N * NF1 * 4);
    float* hh      = (float*)alloc((size_t)N * NF2 * 4 + 64);
    float* dinv    = (float*)alloc((size_t)N * 4);
    int*   rowptr  = (int*)  alloc((size_t)(N + 1) * 4);
    int*   blkhist = (int*)  alloc((size_t)NB * NBLK * 4);
    int*   btot    = (int*)  alloc((size_t)NB * 4);
    int*   bbase   = (int*)  alloc((size_t)(NB + 1) * 4);
    (void)ws_size; (void)n_in; (void)out_size;

    dim3 blk(256);
    int gN  = (N + 255) / 256;
    int gE  = (E + 255) / 256;
    int g16 = (N + 15) / 16;

    // build CSR (no global atomics; offset scan is parallel now)
    coarse_count_kernel<<<NBLK, blk, 0, stream>>>(col, blkhist, E, NB, NBLK);
    bucket_scan_kernel<<<NB, dim3(512), 0, stream>>>(blkhist, btot, NBLK);
    base_scan_kernel<<<1, blk, 0, stream>>>(btot, bbase, rowptr, NB, E, N);
    coarse_scatter_kernel<<<NBLK, blk, 0, stream>>>(row, col, ew, blkhist, bbase, pool, E, NB, NBLK);
    fine_sort_kernel<<<NB, dim3(1024), 0, stream>>>(pool, bbase, csr, rowptr, dinv, N);
    norm_xform_kernel<<<gE, blk, 0, stream>>>(csr, dinv, E);

    // layer 1
    gemm1_kernel<<<g16, blk, 0, stream>>>(x, W1, h, N);
    gather1_kernel<<<g16, blk, 0, stream>>>(csr, rowptr, dinv, h, b1, x1, N);

    // layer 2
    gemm2_kernel<<<gN, blk, 0, stream>>>(x1, W2, hh, N);
    gather2_lsm_kernel<<<g16, blk, 0, stream>>>(csr, rowptr, dinv, hh, b2, logits, N);
}

// Round 5
// 378.665 us; speedup vs baseline: 1.9758x; 1.0662x over previous
//
#include <hip/hip_runtime.h>
#include <hip/hip_bf16.h>

// GCN 2-layer forward on MI355X — CSR via two-level LDS counting sort
// (zero global atomics). Round-5 change: gemm1 rewritten as register-blocked
// skinny GEMM: coalesced x staging into transposed LDS tile (stride 257,
// conflict-free), W1 via wave-uniform s_load into SGPRs, 16 FMA per ds_read
// (was 167 us issue-bound; target ~40 us memory-bound).
// Inputs: x[N,512] f32, edge_index[2,E] int32, edge_weight[E] f32,
//         W1[512,16], b1[16], W2[16,10], b2[10]
// Outputs (concat): log_softmax(logits)[N,10], x1[N,16]

#define NF1 16   // hidden
#define NF2 10   // classes
#define FIN 512
#define EPB 8192 // edges per coarse block (256 thr * 32)
#define KB  32   // gemm1 K-chunk
#define ATS 257  // transposed-tile row stride (2-way bank alias max = free)

typedef unsigned long long ull;

// ---------- A: coarse count (col>>9) into per-block histograms ----------
// blkhist layout TRANSPOSED: blkhist[bucket*NBLK + blk] so the per-bucket
// scan reads contiguously.
__global__ __launch_bounds__(256) void coarse_count_kernel(const int* __restrict__ col,
                                                           int* __restrict__ blkhist,
                                                           int E, int NB, int NBLK) {
    __shared__ int lh[256];
    int t = threadIdx.x;
    lh[t] = 0;
    __syncthreads();
    int base = blockIdx.x * EPB;
    int cnt = min(EPB, E - base);
    for (int i = t; i < cnt; i += 256)
        atomicAdd(&lh[col[base + i] >> 9], 1);
    __syncthreads();
    if (t < NB) blkhist[t * NBLK + blockIdx.x] = lh[t];
}

// ---------- B1: per-bucket exclusive scan over blocks (parallel) ----------
__global__ __launch_bounds__(512) void bucket_scan_kernel(int* __restrict__ blkhist,
                                                          int* __restrict__ btot,
                                                          int NBLK) {
    __shared__ int s[512];
    int t = threadIdx.x;
    int* p = blkhist + (size_t)blockIdx.x * NBLK;
    int carry = 0;
    for (int base = 0; base < NBLK; base += 512) {
        int idx = base + t;
        int v = (idx < NBLK) ? p[idx] : 0;
        s[t] = v;
        __syncthreads();
        for (int off = 1; off < 512; off <<= 1) {   // inclusive Hillis-Steele
            int u = (t >= off) ? s[t - off] : 0;
            __syncthreads();
            s[t] += u;
            __syncthreads();
        }
        if (idx < NBLK) p[idx] = s[t] - v + carry;  // exclusive within bucket
        carry += s[511];
        __syncthreads();
    }
    if (t == 0) btot[blockIdx.x] = carry;
}

// ---------- B2: scan bucket totals -> bbase ----------
__global__ __launch_bounds__(256) void base_scan_kernel(const int* __restrict__ btot,
                                                        int* __restrict__ bbase,
                                                        int* __restrict__ rowptr,
                                                        int NB, int E, int N) {
    __shared__ int s[256];
    int t = threadIdx.x;
    int v = (t < NB) ? btot[t] : 0;
    s[t] = v;
    __syncthreads();
    for (int off = 1; off < 256; off <<= 1) {
        int u = (t >= off) ? s[t - off] : 0;
        __syncthreads();
        s[t] += u;
        __syncthreads();
    }
    if (t < NB) bbase[t] = s[t] - v;
    if (t == 0) { bbase[NB] = E; rowptr[N] = E; }
}

// ---------- C: coarse scatter into bucket-ordered pool ----------
// pool entry: hi32 = (c9<<20)|row, lo32 = weight bits
__global__ __launch_bounds__(256) void coarse_scatter_kernel(const int* __restrict__ row,
                                                             const int* __restrict__ col,
                                                             const float* __restrict__ ew,
                                                             const int* __restrict__ blkhist,
                                                             const int* __restrict__ bbase,
                                                             ull* __restrict__ pool,
                                                             int E, int NB, int NBLK) {
    __shared__ int cur[256];
    int t = threadIdx.x;
    if (t < NB) cur[t] = blkhist[t * NBLK + blockIdx.x] + bbase[t];
    __syncthreads();
    int base = blockIdx.x * EPB;
    int cnt = min(EPB, E - base);
    for (int i = t; i < cnt; i += 256) {
        int e = base + i;
        int c = col[e], r = row[e];
        float w = ew[e];
        int b = c >> 9, c9 = c & 511;
        int pos = atomicAdd(&cur[b], 1);
        pool[pos] = ((ull)((((unsigned)c9) << 20) | (unsigned)r) << 32) | (ull)__float_as_uint(w);
    }
}

// ---------- D: fine sort within bucket (512 cols) -> CSR, rowptr, dinv ----------
// csr entry: hi32 = weight bits, lo32 = src row
__global__ __launch_bounds__(1024) void fine_sort_kernel(const ull* __restrict__ pool,
                                                         const int* __restrict__ bbase,
                                                         ull* __restrict__ csr,
                                                         int* __restrict__ rowptr,
                                                         float* __restrict__ dinv, int N) {
    __shared__ int hist[512];
    __shared__ float wsum[512];
    __shared__ int cur[512];
    int t = threadIdx.x;
    int b = blockIdx.x;
    int bb = bbase[b], be = bbase[b + 1];
    int Ki = be - bb;
    if (t < 512) { hist[t] = 0; wsum[t] = 0.0f; }
    __syncthreads();
    for (int i = t; i < Ki; i += 1024) {
        ull p = pool[bb + i];
        unsigned hi = (unsigned)(p >> 32);
        int c9 = (hi >> 20) & 511;
        atomicAdd(&hist[c9], 1);
        atomicAdd(&wsum[c9], __uint_as_float((unsigned)p));
    }
    __syncthreads();
    int own = (t < 512) ? hist[t] : 0;
    if (t < 512) cur[t] = own;
    __syncthreads();
    for (int off = 1; off < 512; off <<= 1) {   // inclusive scan
        int v = (t >= off && t < 512) ? cur[t - off] : 0;
        __syncthreads();
        if (t < 512) cur[t] += v;
        __syncthreads();
    }
    int excl = (t < 512) ? (cur[t] - own) : 0;
    if (t < 512) cur[t] = excl;                 // own-cell only: no race
    int c = (b << 9) + t;
    if (t < 512 && c < N) {
        rowptr[c] = bb + excl;
        dinv[c] = rsqrtf(1.0f + wsum[t]);       // deg = self(1) + sum(w) >= 1
    }
    __syncthreads();
    for (int i = t; i < Ki; i += 1024) {        // place (pool range is L2-hot)
        ull p = pool[bb + i];
        unsigned hi = (unsigned)(p >> 32);
        int c9 = (hi >> 20) & 511;
        unsigned r = hi & 0xFFFFFu;
        int k = atomicAdd(&cur[c9], 1);
        csr[bb + k] = ((p & 0xFFFFFFFFull) << 32) | (ull)r;
    }
}

// ---------- F: fold dinv[row] into stored weight ----------
__global__ __launch_bounds__(256) void norm_xform_kernel(ull* __restrict__ csr,
                                                         const float* __restrict__ dinv, int E) {
    int i = blockIdx.x * 256 + threadIdx.x;
    if (i >= E) return;
    ull v = csr[i];
    unsigned r = (unsigned)v;
    float w = __uint_as_float((unsigned)(v >> 32)) * dinv[r];
    csr[i] = ((ull)__float_as_uint(w) << 32) | (ull)r;
}

// ---------- GEMM1: h = x @ W1   [N,512]@[512,16] ----------
// 256 rows/block. x staged coalesced into transposed LDS tile At[KB][ATS]
// (stride 257: max 2-way bank alias on both write and read = free).
// W1 accessed wave-uniformly -> s_load into SGPRs, v_fmac v,s,v.
// Per k-step: 1 ds_read_b32 + 16 FMA.
__global__ __launch_bounds__(256) void gemm1_kernel(const float* __restrict__ x,
                                                    const float* __restrict__ W1,
                                                    float* __restrict__ h, int N) {
    __shared__ float At[KB * ATS];
    int tid = threadIdx.x;
    int blockBase = blockIdx.x * 256;
    int myRow = blockBase + tid;

    float acc[NF1];
#pragma unroll
    for (int f = 0; f < NF1; f++) acc[f] = 0.0f;

    int kq = tid & 7;    // float4 slot within 32-float chunk of one row
    int rt = tid >> 3;   // row-within-pass (0..31)

    for (int kc = 0; kc < FIN; kc += KB) {
        __syncthreads();
        // stage 256 rows x KB floats, coalesced (8 lanes * 16B = 128B/row seg)
#pragma unroll
        for (int p = 0; p < 8; p++) {
            int r = p * 32 + rt;             // row offset within block
            int grow = blockBase + r;
            if (grow < N) {
                float4 xv = *reinterpret_cast<const float4*>(
                    &x[(size_t)grow * FIN + kc + 4 * kq]);
                At[(4 * kq + 0) * ATS + r] = xv.x;
                At[(4 * kq + 1) * ATS + r] = xv.y;
                At[(4 * kq + 2) * ATS + r] = xv.z;
                At[(4 * kq + 3) * ATS + r] = xv.w;
            }
        }
        __syncthreads();
        // compute: each thread owns row `tid` of the tile
#pragma unroll 4
        for (int k = 0; k < KB; k++) {
            float a = At[k * ATS + tid];
#pragma unroll
            for (int f = 0; f < NF1; f++)
                acc[f] = fmaf(a, W1[(kc + k) * NF1 + f], acc[f]);
        }
    }

    if (myRow < N) {
        float* hp = &h[(size_t)myRow * NF1];
#pragma unroll
        for (int q = 0; q < 4; q++) {
            float4 o = make_float4(acc[4 * q], acc[4 * q + 1], acc[4 * q + 2], acc[4 * q + 3]);
            *reinterpret_cast<float4*>(hp + 4 * q) = o;
        }
    }
}

// ---------- gather layer 1: x1[c] = b1 + dinv[c]*(sum s_i*h[r_i] + dinv[c]*h[c]) ----------
__global__ __launch_bounds__(256) void gather1_kernel(const ull* __restrict__ csr,
                                                      const int* __restrict__ rowptr,
                                                      const float* __restrict__ dinv,
                                                      const float* __restrict__ h,
                                                      const float* __restrict__ b1,
                                                      float* __restrict__ x1, int N) {
    int t = blockIdx.x * 256 + threadIdx.x;
    int node = t >> 4, f = t & 15;
    if (node >= N) return;
    int s = rowptr[node], e = rowptr[node + 1];
    float di = dinv[node];
    float acc = di * h[(size_t)node * NF1 + f];   // self-loop term (w=1)
    int i = s;
    for (; i + 1 < e; i += 2) {
        ull v0 = csr[i], v1 = csr[i + 1];
        int r0 = (int)(v0 & 0xffffffffull); float w0 = __uint_as_float((unsigned)(v0 >> 32));
        int r1 = (int)(v1 & 0xffffffffull); float w1 = __uint_as_float((unsigned)(v1 >> 32));
        acc += w0 * h[(size_t)r0 * NF1 + f];
        acc += w1 * h[(size_t)r1 * NF1 + f];
    }
    if (i < e) {
        ull v = csr[i];
        int r = (int)(v & 0xffffffffull); float w = __uint_as_float((unsigned)(v >> 32));
        acc += w * h[(size_t)r * NF1 + f];
    }
    x1[(size_t)node * NF1 + f] = b1[f] + di * acc;
}

// ---------- GEMM2: hh = relu(x1) @ W2   [N,16]@[16,10] ----------
__global__ __launch_bounds__(256) void gemm2_kernel(const float* __restrict__ x1,
                                                    const float* __restrict__ W2,
                                                    float* __restrict__ hh, int N) {
    int j = blockIdx.x * 256 + threadIdx.x;
    if (j >= N) return;
    float xr[NF1];
#pragma unroll
    for (int f = 0; f < NF1; f++) xr[f] = fmaxf(x1[(size_t)j * NF1 + f], 0.0f);
#pragma unroll
    for (int c = 0; c < NF2; c++) {
        float acc = 0.0f;
#pragma unroll
        for (int f = 0; f < NF1; f++) acc += xr[f] * W2[f * NF2 + c];
        hh[(size_t)j * NF2 + c] = acc;
    }
}

// ---------- gather layer 2 + fused log-softmax ----------
__global__ __launch_bounds__(256) void gather2_lsm_kernel(const ull* __restrict__ csr,
                                                          const int* __restrict__ rowptr,
                                                          const float* __restrict__ dinv,
                                                          const float* __restrict__ hh,
                                                          const float* __restrict__ b2,
                                                          float* __restrict__ out, int N) {
    int t = blockIdx.x * 256 + threadIdx.x;
    int node = t >> 4, f = t & 15;
    bool act = (node < N) && (f < NF2);
    float acc = 0.0f;
    if (node < N) {
        int s = rowptr[node], e = rowptr[node + 1];
        float di = dinv[node];
        acc = act ? di * hh[(size_t)node * NF2 + f] : 0.0f;  // self-loop term
        int i = s;
        for (; i + 1 < e; i += 2) {
            ull v0 = csr[i], v1 = csr[i + 1];
            int r0 = (int)(v0 & 0xffffffffull); float w0 = __uint_as_float((unsigned)(v0 >> 32));
            int r1 = (int)(v1 & 0xffffffffull); float w1 = __uint_as_float((unsigned)(v1 >> 32));
            float h0 = (f < NF2) ? hh[(size_t)r0 * NF2 + f] : 0.0f;
            float h1 = (f < NF2) ? hh[(size_t)r1 * NF2 + f] : 0.0f;
            acc += w0 * h0 + w1 * h1;
        }
        if (i < e) {
            ull v = csr[i];
            int r = (int)(v & 0xffffffffull); float w = __uint_as_float((unsigned)(v >> 32));
            float hv = (f < NF2) ? hh[(size_t)r * NF2 + f] : 0.0f;
            acc += w * hv;
        }
        acc = b2[f] + di * acc;  // logits (garbage in lanes f>=10, masked below)
    }
    // log-softmax across the 16-lane group (10 active lanes)
    float m = act ? acc : -INFINITY;
#pragma unroll
    for (int off = 1; off < 16; off <<= 1) m = fmaxf(m, __shfl_xor(m, off, 16));
    float p = act ? expf(acc - m) : 0.0f;
    float ssum = p;
#pragma unroll
    for (int off = 1; off < 16; off <<= 1) ssum += __shfl_xor(ssum, off, 16);
    if (act) out[(size_t)node * NF2 + f] = acc - m - logf(ssum);
}

extern "C" void kernel_launch(void* const* d_in, const int* in_sizes, int n_in,
                              void* d_out, int out_size, void* d_ws, size_t ws_size,
                              hipStream_t stream) {
    const float* x  = (const float*)d_in[0];
    const int*   ei = (const int*)d_in[1];
    const float* ew = (const float*)d_in[2];
    const float* W1 = (const float*)d_in[3];
    const float* b1 = (const float*)d_in[4];
    const float* W2 = (const float*)d_in[5];
    const float* b2 = (const float*)d_in[6];

    const int E = in_sizes[2];           // 3,200,000
    const int N = in_sizes[0] / FIN;     // 100,000
    const int* row = ei;
    const int* col = ei + E;

    const int NB   = (N + 511) >> 9;     // coarse buckets (196)
    const int NBLK = (E + EPB - 1) / EPB;

    float* out    = (float*)d_out;
    float* logits = out;                        // [N,10]
    float* x1     = out + (size_t)N * NF2;      // [N,16]

    char* ws = (char*)d_ws;
    size_t off = 0;
    auto alloc = [&](size_t bytes) { void* p = ws + off; off += (bytes + 255) / 256 * 256; return p; };
    ull*   pool    = (ull*)  alloc((size_t)E * 8);
    ull*   csr     = (ull*)  alloc((size_t)E * 8);
    float* h       = (float*)alloc((size_t)N * NF1 * 4);
    float* hh      = (float*)alloc((size_t)N * NF2 * 4 + 64);
    float* dinv    = (float*)alloc((size_t)N * 4);
    int*   rowptr  = (int*)  alloc((size_t)(N + 1) * 4);
    int*   blkhist = (int*)  alloc((size_t)NB * NBLK * 4);
    int*   btot    = (int*)  alloc((size_t)NB * 4);
    int*   bbase   = (int*)  alloc((size_t)(NB + 1) * 4);
    (void)ws_size; (void)n_in; (void)out_size;

    dim3 blk(256);
    int gN  = (N + 255) / 256;
    int gE  = (E + 255) / 256;
    int g16 = (N + 15) / 16;
    int gB  = (N + 255) / 256;   // gemm1 blocks (256 rows each)

    // build CSR (no global atomics; offset scan is parallel)
    coarse_count_kernel<<<NBLK, blk, 0, stream>>>(col, blkhist, E, NB, NBLK);
    bucket_scan_kernel<<<NB, dim3(512), 0, stream>>>(blkhist, btot, NBLK);
    base_scan_kernel<<<1, blk, 0, stream>>>(btot, bbase, rowptr, NB, E, N);
    coarse_scatter_kernel<<<NBLK, blk, 0, stream>>>(row, col, ew, blkhist, bbase, pool, E, NB, NBLK);
    fine_sort_kernel<<<NB, dim3(1024), 0, stream>>>(pool, bbase, csr, rowptr, dinv, N);
    norm_xform_kernel<<<gE, blk, 0, stream>>>(csr, dinv, E);

    // layer 1
    gemm1_kernel<<<gB, blk, 0, stream>>>(x, W1, h, N);
    gather1_kernel<<<g16, blk, 0, stream>>>(csr, rowptr, dinv, h, b1, x1, N);

    // layer 2
    gemm2_kernel<<<gN, blk, 0, stream>>>(x1, W2, hh, N);
    gather2_lsm_kernel<<<g16, blk, 0, stream>>>(csr, rowptr, dinv, hh, b2, logits, N);
}

// Round 6
// 344.404 us; speedup vs baseline: 2.1724x; 1.0995x over previous
//
#include <hip/hip_runtime.h>
#include <hip/hip_bf16.h>

// GCN 2-layer forward on MI355X — CSR via two-level LDS counting sort
// (zero global atomics). Round-6: gemm1 is a no-LDS register GEMM
// (x via global_load/vmcnt, W1 via s_load/lgkmcnt — never mixed with ds_read,
// which forced lgkmcnt(0) drains in round 5), split-K=2 for occupancy.
// dinv[row] is folded into h'/hh' at GEMM epilogues, so the CSR stores raw
// edge weights and the norm_xform pass is deleted.
// Inputs: x[N,512] f32, edge_index[2,E] int32, edge_weight[E] f32,
//         W1[512,16], b1[16], W2[16,10], b2[10]
// Outputs (concat): log_softmax(logits)[N,10], x1[N,16]

#define NF1 16   // hidden
#define NF2 10   // classes
#define FIN 512
#define EPB 8192 // edges per coarse block (256 thr * 32)

typedef unsigned long long ull;

// ---------- A: coarse count (col>>9) into per-block histograms ----------
__global__ __launch_bounds__(256) void coarse_count_kernel(const int* __restrict__ col,
                                                           int* __restrict__ blkhist,
                                                           int E, int NB, int NBLK) {
    __shared__ int lh[256];
    int t = threadIdx.x;
    lh[t] = 0;
    __syncthreads();
    int base = blockIdx.x * EPB;
    int cnt = min(EPB, E - base);
    for (int i = t; i < cnt; i += 256)
        atomicAdd(&lh[col[base + i] >> 9], 1);
    __syncthreads();
    if (t < NB) blkhist[t * NBLK + blockIdx.x] = lh[t];
}

// ---------- B1: per-bucket exclusive scan over blocks (parallel) ----------
__global__ __launch_bounds__(512) void bucket_scan_kernel(int* __restrict__ blkhist,
                                                          int* __restrict__ btot,
                                                          int NBLK) {
    __shared__ int s[512];
    int t = threadIdx.x;
    int* p = blkhist + (size_t)blockIdx.x * NBLK;
    int carry = 0;
    for (int base = 0; base < NBLK; base += 512) {
        int idx = base + t;
        int v = (idx < NBLK) ? p[idx] : 0;
        s[t] = v;
        __syncthreads();
        for (int off = 1; off < 512; off <<= 1) {
            int u = (t >= off) ? s[t - off] : 0;
            __syncthreads();
            s[t] += u;
            __syncthreads();
        }
        if (idx < NBLK) p[idx] = s[t] - v + carry;
        carry += s[511];
        __syncthreads();
    }
    if (t == 0) btot[blockIdx.x] = carry;
}

// ---------- B2: scan bucket totals -> bbase ----------
__global__ __launch_bounds__(256) void base_scan_kernel(const int* __restrict__ btot,
                                                        int* __restrict__ bbase,
                                                        int* __restrict__ rowptr,
                                                        int NB, int E, int N) {
    __shared__ int s[256];
    int t = threadIdx.x;
    int v = (t < NB) ? btot[t] : 0;
    s[t] = v;
    __syncthreads();
    for (int off = 1; off < 256; off <<= 1) {
        int u = (t >= off) ? s[t - off] : 0;
        __syncthreads();
        s[t] += u;
        __syncthreads();
    }
    if (t < NB) bbase[t] = s[t] - v;
    if (t == 0) { bbase[NB] = E; rowptr[N] = E; }
}

// ---------- C: coarse scatter into bucket-ordered pool ----------
// pool entry: hi32 = (c9<<20)|row, lo32 = weight bits
__global__ __launch_bounds__(256) void coarse_scatter_kernel(const int* __restrict__ row,
                                                             const int* __restrict__ col,
                                                             const float* __restrict__ ew,
                                                             const int* __restrict__ blkhist,
                                                             const int* __restrict__ bbase,
                                                             ull* __restrict__ pool,
                                                             int E, int NB, int NBLK) {
    __shared__ int cur[256];
    int t = threadIdx.x;
    if (t < NB) cur[t] = blkhist[t * NBLK + blockIdx.x] + bbase[t];
    __syncthreads();
    int base = blockIdx.x * EPB;
    int cnt = min(EPB, E - base);
    for (int i = t; i < cnt; i += 256) {
        int e = base + i;
        int c = col[e], r = row[e];
        float w = ew[e];
        int b = c >> 9, c9 = c & 511;
        int pos = atomicAdd(&cur[b], 1);
        pool[pos] = ((ull)((((unsigned)c9) << 20) | (unsigned)r) << 32) | (ull)__float_as_uint(w);
    }
}

// ---------- D: fine sort within bucket (512 cols) -> CSR (raw w), rowptr, dinv ----------
__global__ __launch_bounds__(1024) void fine_sort_kernel(const ull* __restrict__ pool,
                                                         const int* __restrict__ bbase,
                                                         ull* __restrict__ csr,
                                                         int* __restrict__ rowptr,
                                                         float* __restrict__ dinv, int N) {
    __shared__ int hist[512];
    __shared__ float wsum[512];
    __shared__ int cur[512];
    int t = threadIdx.x;
    int b = blockIdx.x;
    int bb = bbase[b], be = bbase[b + 1];
    int Ki = be - bb;
    if (t < 512) { hist[t] = 0; wsum[t] = 0.0f; }
    __syncthreads();
    for (int i = t; i < Ki; i += 1024) {
        ull p = pool[bb + i];
        unsigned hi = (unsigned)(p >> 32);
        int c9 = (hi >> 20) & 511;
        atomicAdd(&hist[c9], 1);
        atomicAdd(&wsum[c9], __uint_as_float((unsigned)p));
    }
    __syncthreads();
    int own = (t < 512) ? hist[t] : 0;
    if (t < 512) cur[t] = own;
    __syncthreads();
    for (int off = 1; off < 512; off <<= 1) {
        int v = (t >= off && t < 512) ? cur[t - off] : 0;
        __syncthreads();
        if (t < 512) cur[t] += v;
        __syncthreads();
    }
    int excl = (t < 512) ? (cur[t] - own) : 0;
    if (t < 512) cur[t] = excl;
    int c = (b << 9) + t;
    if (t < 512 && c < N) {
        rowptr[c] = bb + excl;
        dinv[c] = rsqrtf(1.0f + wsum[t]);       // deg = self(1) + sum(w)
    }
    __syncthreads();
    for (int i = t; i < Ki; i += 1024) {
        ull p = pool[bb + i];
        unsigned hi = (unsigned)(p >> 32);
        int c9 = (hi >> 20) & 511;
        unsigned r = hi & 0xFFFFFu;
        int k = atomicAdd(&cur[c9], 1);
        csr[bb + k] = ((p & 0xFFFFFFFFull) << 32) | (ull)r;   // raw weight
    }
}

// ---------- GEMM1 (split-K=2, no LDS): part[half][row][f] ----------
// x via per-lane global_load_dwordx4 (vmcnt); W1 via uniform s_load (lgkmcnt).
// The two never share a counter, so both streams pipeline deep.
__global__ __launch_bounds__(256) void gemm1_kernel(const float* __restrict__ x,
                                                    const float* __restrict__ W1,
                                                    float* __restrict__ part,
                                                    int N, int nbRow) {
    int b = blockIdx.x;
    int half = (b >= nbRow) ? 1 : 0;
    int rb = b - half * nbRow;
    int row = rb * 256 + threadIdx.x;
    if (row >= N) return;
    const int k0 = half * (FIN / 2);

    float acc[NF1];
#pragma unroll
    for (int f = 0; f < NF1; f++) acc[f] = 0.0f;

    const float* xr = x + (size_t)row * FIN + k0;
    const float* wp = W1 + (size_t)k0 * NF1;

#pragma unroll 2
    for (int k = 0; k < FIN / 2; k += 4) {
        float4 a = *reinterpret_cast<const float4*>(xr + k);
#pragma unroll
        for (int kk = 0; kk < 4; kk++) {
            float av = (&a.x)[kk];
#pragma unroll
            for (int f = 0; f < NF1; f++)
                acc[f] = fmaf(av, wp[(k + kk) * NF1 + f], acc[f]);
        }
    }

    float* pp = part + ((size_t)half * N + row) * NF1;
#pragma unroll
    for (int q = 0; q < 4; q++) {
        float4 o = make_float4(acc[4 * q], acc[4 * q + 1], acc[4 * q + 2], acc[4 * q + 3]);
        *reinterpret_cast<float4*>(pp + 4 * q) = o;
    }
}

// ---------- combine split-K partials and fold dinv: h' = dinv[row]*(p0+p1) ----------
__global__ __launch_bounds__(256) void combine_scale_kernel(const float* __restrict__ part,
                                                            const float* __restrict__ dinv,
                                                            float* __restrict__ hs, int N) {
    int i4 = blockIdx.x * 256 + threadIdx.x;     // float4 index
    int total = N * NF1 / 4;
    if (i4 >= total) return;
    int rowIdx = (i4 << 2) >> 4;                 // 4 floats stay within one row
    float4 a = reinterpret_cast<const float4*>(part)[i4];
    float4 bq = reinterpret_cast<const float4*>(part + (size_t)N * NF1)[i4];
    float d = dinv[rowIdx];
    float4 o = make_float4(d * (a.x + bq.x), d * (a.y + bq.y),
                           d * (a.z + bq.z), d * (a.w + bq.w));
    reinterpret_cast<float4*>(hs)[i4] = o;
}

// ---------- gather layer 1: x1[c] = b1 + di*( sum ew_i*h'[r_i] + h'[c] ) ----------
__global__ __launch_bounds__(256) void gather1_kernel(const ull* __restrict__ csr,
                                                      const int* __restrict__ rowptr,
                                                      const float* __restrict__ dinv,
                                                      const float* __restrict__ hs,
                                                      const float* __restrict__ b1,
                                                      float* __restrict__ x1, int N) {
    int t = blockIdx.x * 256 + threadIdx.x;
    int node = t >> 4, f = t & 15;
    if (node >= N) return;
    int s = rowptr[node], e = rowptr[node + 1];
    float di = dinv[node];
    float acc = hs[(size_t)node * NF1 + f];       // self-loop: h'[c]
    int i = s;
    for (; i + 1 < e; i += 2) {
        ull v0 = csr[i], v1 = csr[i + 1];
        int r0 = (int)(v0 & 0xffffffffull); float w0 = __uint_as_float((unsigned)(v0 >> 32));
        int r1 = (int)(v1 & 0xffffffffull); float w1 = __uint_as_float((unsigned)(v1 >> 32));
        acc += w0 * hs[(size_t)r0 * NF1 + f];
        acc += w1 * hs[(size_t)r1 * NF1 + f];
    }
    if (i < e) {
        ull v = csr[i];
        int r = (int)(v & 0xffffffffull); float w = __uint_as_float((unsigned)(v >> 32));
        acc += w * hs[(size_t)r * NF1 + f];
    }
    x1[(size_t)node * NF1 + f] = b1[f] + di * acc;
}

// ---------- GEMM2: hh' = dinv[j] * (relu(x1[j]) @ W2) ----------
__global__ __launch_bounds__(256) void gemm2_kernel(const float* __restrict__ x1,
                                                    const float* __restrict__ W2,
                                                    const float* __restrict__ dinv,
                                                    float* __restrict__ hh, int N) {
    int j = blockIdx.x * 256 + threadIdx.x;
    if (j >= N) return;
    float xr[NF1];
#pragma unroll
    for (int f = 0; f < NF1; f++) xr[f] = fmaxf(x1[(size_t)j * NF1 + f], 0.0f);
    float d = dinv[j];
#pragma unroll
    for (int c = 0; c < NF2; c++) {
        float acc = 0.0f;
#pragma unroll
        for (int f = 0; f < NF1; f++) acc += xr[f] * W2[f * NF2 + c];
        hh[(size_t)j * NF2 + c] = d * acc;
    }
}

// ---------- gather layer 2 + fused log-softmax ----------
__global__ __launch_bounds__(256) void gather2_lsm_kernel(const ull* __restrict__ csr,
                                                          const int* __restrict__ rowptr,
                                                          const float* __restrict__ dinv,
                                                          const float* __restrict__ hh,
                                                          const float* __restrict__ b2,
                                                          float* __restrict__ out, int N) {
    int t = blockIdx.x * 256 + threadIdx.x;
    int node = t >> 4, f = t & 15;
    bool act = (node < N) && (f < NF2);
    float acc = 0.0f;
    if (node < N) {
        int s = rowptr[node], e = rowptr[node + 1];
        float di = dinv[node];
        acc = act ? hh[(size_t)node * NF2 + f] : 0.0f;   // self-loop: hh'[c]
        int i = s;
        for (; i + 1 < e; i += 2) {
            ull v0 = csr[i], v1 = csr[i + 1];
            int r0 = (int)(v0 & 0xffffffffull); float w0 = __uint_as_float((unsigned)(v0 >> 32));
            int r1 = (int)(v1 & 0xffffffffull); float w1 = __uint_as_float((unsigned)(v1 >> 32));
            float h0 = (f < NF2) ? hh[(size_t)r0 * NF2 + f] : 0.0f;
            float h1 = (f < NF2) ? hh[(size_t)r1 * NF2 + f] : 0.0f;
            acc += w0 * h0 + w1 * h1;
        }
        if (i < e) {
            ull v = csr[i];
            int r = (int)(v & 0xffffffffull); float w = __uint_as_float((unsigned)(v >> 32));
            float hv = (f < NF2) ? hh[(size_t)r * NF2 + f] : 0.0f;
            acc += w * hv;
        }
        acc = b2[f] + di * acc;
    }
    // log-softmax across the 16-lane group (10 active lanes)
    float m = act ? acc : -INFINITY;
#pragma unroll
    for (int off = 1; off < 16; off <<= 1) m = fmaxf(m, __shfl_xor(m, off, 16));
    float p = act ? expf(acc - m) : 0.0f;
    float ssum = p;
#pragma unroll
    for (int off = 1; off < 16; off <<= 1) ssum += __shfl_xor(ssum, off, 16);
    if (act) out[(size_t)node * NF2 + f] = acc - m - logf(ssum);
}

extern "C" void kernel_launch(void* const* d_in, const int* in_sizes, int n_in,
                              void* d_out, int out_size, void* d_ws, size_t ws_size,
                              hipStream_t stream) {
    const float* x  = (const float*)d_in[0];
    const int*   ei = (const int*)d_in[1];
    const float* ew = (const float*)d_in[2];
    const float* W1 = (const float*)d_in[3];
    const float* b1 = (const float*)d_in[4];
    const float* W2 = (const float*)d_in[5];
    const float* b2 = (const float*)d_in[6];

    const int E = in_sizes[2];           // 3,200,000
    const int N = in_sizes[0] / FIN;     // 100,000
    const int* row = ei;
    const int* col = ei + E;

    const int NB   = (N + 511) >> 9;     // coarse buckets (196)
    const int NBLK = (E + EPB - 1) / EPB;

    float* out    = (float*)d_out;
    float* logits = out;                        // [N,10]
    float* x1     = out + (size_t)N * NF2;      // [N,16]

    char* ws = (char*)d_ws;
    size_t off = 0;
    auto alloc = [&](size_t bytes) { void* p = ws + off; off += (bytes + 255) / 256 * 256; return p; };
    ull*   pool    = (ull*)  alloc((size_t)E * 8);
    ull*   csr     = (ull*)  alloc((size_t)E * 8);
    float* part    = (float*)alloc((size_t)2 * N * NF1 * 4);   // split-K partials
    float* hs      = (float*)alloc((size_t)N * NF1 * 4);       // h' = dinv*(p0+p1)
    float* hh      = (float*)alloc((size_t)N * NF2 * 4 + 64);  // hh' = dinv*relu(x1)@W2
    float* dinv    = (float*)alloc((size_t)N * 4);
    int*   rowptr  = (int*)  alloc((size_t)(N + 1) * 4);
    int*   blkhist = (int*)  alloc((size_t)NB * NBLK * 4);
    int*   btot    = (int*)  alloc((size_t)NB * 4);
    int*   bbase   = (int*)  alloc((size_t)(NB + 1) * 4);
    (void)ws_size; (void)n_in; (void)out_size;

    dim3 blk(256);
    int gN    = (N + 255) / 256;
    int g16   = (N + 15) / 16;
    int nbRow = (N + 255) / 256;         // gemm1 row-blocks per K-half

    // build CSR (no global atomics)
    coarse_count_kernel<<<NBLK, blk, 0, stream>>>(col, blkhist, E, NB, NBLK);
    bucket_scan_kernel<<<NB, dim3(512), 0, stream>>>(blkhist, btot, NBLK);
    base_scan_kernel<<<1, blk, 0, stream>>>(btot, bbase, rowptr, NB, E, N);
    coarse_scatter_kernel<<<NBLK, blk, 0, stream>>>(row, col, ew, blkhist, bbase, pool, E, NB, NBLK);
    fine_sort_kernel<<<NB, dim3(1024), 0, stream>>>(pool, bbase, csr, rowptr, dinv, N);

    // layer 1
    gemm1_kernel<<<2 * nbRow, blk, 0, stream>>>(x, W1, part, N, nbRow);
    combine_scale_kernel<<<(N * NF1 / 4 + 255) / 256, blk, 0, stream>>>(part, dinv, hs, N);
    gather1_kernel<<<g16, blk, 0, stream>>>(csr, rowptr, dinv, hs, b1, x1, N);

    // layer 2
    gemm2_kernel<<<gN, blk, 0, stream>>>(x1, W2, dinv, hh, N);
    gather2_lsm_kernel<<<g16, blk, 0, stream>>>(csr, rowptr, dinv, hh, b2, logits, N);
}